// Round 14
// baseline (318.035 us; speedup 1.0000x reference)
//
#include <hip/hip_runtime.h>
#include <hip/hip_bf16.h>

#define D 128
#define GRP 64            // nodes per group
#define NBMAX 4096        // max groups supported by fast path (N <= 256K)
#define CAPB_MAX 2048     // per-group capacity
#define STAGE_E 8192      // per-chunk LDS staging (edges)

typedef __attribute__((ext_vector_type(8))) short short8;
typedef __attribute__((ext_vector_type(4))) float f32x4;

__device__ __forceinline__ float bf2f(unsigned short u) {
    union { unsigned int i; float f; } c;
    c.i = ((unsigned int)u) << 16;
    return c.f;
}
__device__ __forceinline__ float bits2f(unsigned int i) {
    union { unsigned int i; float f; } c;
    c.i = i;
    return c.f;
}
__device__ __forceinline__ unsigned short f2bf(float f) {
    __hip_bfloat16 h = __float2bfloat16(f);
    return *(unsigned short*)&h;
}

// ---- per-block dtype probes (fast path; no separate probe dispatch) ----
__device__ __forceinline__ int block_probe_xf32(const unsigned short* x) {
    __shared__ int cntS;
    if (threadIdx.x == 0) cntS = 0;
    __syncthreads();
    int bad = 0;
    for (int i = threadIdx.x; i < 512; i += blockDim.x) {
        float v = bf2f(x[i]);
        if (!(fabsf(v) < 1e4f)) bad++;
    }
    if (bad) atomicAdd(&cntS, bad);
    __syncthreads();
    int r = (cntS > 2) ? 1 : 0;
    __syncthreads();
    return r;
}
__device__ __forceinline__ int block_probe_i64(const void* eiv, int nNodes) {
    __shared__ int okS;
    if (threadIdx.x == 0) okS = 1;
    __syncthreads();
    if (threadIdx.x < 64) {
        long long v = ((const long long*)eiv)[threadIdx.x];
        if (v < 0 || v >= (long long)nNodes) atomicAnd(&okS, 0);
    }
    __syncthreads();
    int r = okS;
    __syncthreads();
    return r;
}

// Probe kernel retained for the fallback path only.
__global__ __launch_bounds__(64) void probe_kernel(
    const unsigned short* __restrict__ x,
    const long long* __restrict__ ei64,
    int nNodes, int* __restrict__ flags)
{
    const int lane = threadIdx.x;
    int cnt = 0;
    for (int i = lane; i < 512; i += 64) {
        float v = bf2f(x[i]);
        if (!(fabsf(v) < 1e4f)) cnt++;
    }
    unsigned long long m1 = __ballot(cnt > 0);
    long long v = ei64[lane];
    int bad = (v < 0 || v >= (long long)nNodes) ? 1 : 0;
    unsigned long long m2 = __ballot(bad);
    if (lane == 0) {
        flags[0] = (__popcll(m1) > 2) ? 1 : 0;
        flags[1] = (m2 == 0) ? 1 : 0;
    }
}

// ---------- fast-path GEMM: y = x @ W via MFMA (fp32 -> hi/lo bf16 split) ----------
// 512-thread blocks: 8 waves share the 64KB Wh/Wl LDS -> 2 blocks/CU = 4 waves/SIMD
// (2x TLP vs 256-thread version; gemm was latency-bound at 2 waves/SIMD).
// Also zeroes gcnt/ovfCnt and sets ovfHead=-1 (stream order covers bin_edges).
__global__ __launch_bounds__(512, 4) void gemm_mfma(
    const void* __restrict__ xv, const void* __restrict__ Wv, void* __restrict__ yv,
    int nNodes, int nTiles,
    int* __restrict__ zbase, int zInts, int* __restrict__ mhead, int NB)
{
    __shared__ unsigned short Wth[D * D];   // 32 KB: hi(W)^T, swizzled
    __shared__ unsigned short Wtl[D * D];   // 32 KB: lo(W)^T (fp32 mode only)

    const int tid = threadIdx.x;

    // fold the old hipMemsetAsync calls into this kernel's prologue
    for (int i = blockIdx.x * 512 + tid; i < zInts; i += gridDim.x * 512) zbase[i] = 0;
    for (int i = blockIdx.x * 512 + tid; i < NB; i += gridDim.x * 512) mhead[i] = -1;

    const int xf32 = block_probe_xf32((const unsigned short*)xv);
    const int w = tid >> 6, l = tid & 63;
    const int lr = l & 15, g = l >> 4;

    if (xf32) {
        const float* W = (const float*)Wv;
        for (int i = tid; i < D * D; i += 512) {
            int c = i & 127, k = i >> 7;     // coalesced read (consecutive c)
            float wv = W[(size_t)k * D + c];
            unsigned short hi = f2bf(wv);
            unsigned short lo = f2bf(wv - bf2f(hi));
            int ba = (((c << 7) + k) << 1) ^ ((c & 7) << 4);
            *(unsigned short*)((char*)Wth + ba) = hi;
            *(unsigned short*)((char*)Wtl + ba) = lo;
        }
    } else {
        const unsigned short* W = (const unsigned short*)Wv;
        for (int i = tid; i < D * D / 2; i += 512) {
            int c = i & 127, k2 = i >> 7;
            unsigned int v0 = W[(size_t)(2 * k2) * D + c];
            unsigned int v1 = W[(size_t)(2 * k2 + 1) * D + c];
            unsigned int pk = v0 | (v1 << 16);
            int ba = (((c << 7) + 2 * k2) << 1) ^ ((c & 7) << 4);
            *(unsigned int*)((char*)Wth + ba) = pk;
        }
    }
    __syncthreads();

    unsigned short* y = (unsigned short*)yv;

    for (int t = blockIdx.x; t < nTiles; t += gridDim.x) {
        const int row0 = t * 128 + w * 16;   // 8 waves x 16 rows = 128-row tile
        int arow = row0 + lr; if (arow >= nNodes) arow = nNodes - 1;

        short8 ah[4], al[4];
        if (xf32) {
            const float* xr = (const float*)xv + (size_t)arow * D;
            #pragma unroll
            for (int kk = 0; kk < 4; ++kk) {
                float f[8];
                *(float4*)&f[0] = *(const float4*)(xr + kk * 32 + g * 8);
                *(float4*)&f[4] = *(const float4*)(xr + kk * 32 + g * 8 + 4);
                #pragma unroll
                for (int i = 0; i < 8; ++i) {
                    unsigned short hi = f2bf(f[i]);
                    ah[kk][i] = (short)hi;
                    al[kk][i] = (short)f2bf(f[i] - bf2f(hi));
                }
            }
        } else {
            const char* xrow = (const char*)xv + (size_t)arow * (D * 2);
            #pragma unroll
            for (int kk = 0; kk < 4; ++kk)
                ah[kk] = *(const short8*)(xrow + (kk << 6) + (g << 4));
        }

        #pragma unroll
        for (int c = 0; c < 8; ++c) {
            const int col = c * 16 + lr;
            f32x4 acc = {0.f, 0.f, 0.f, 0.f};
            #pragma unroll
            for (int kk = 0; kk < 4; ++kk) {
                int ba = ((col << 8) + (kk << 6) + (g << 4)) ^ ((col & 7) << 4);
                short8 bh = *(const short8*)((const char*)Wth + ba);
                acc = __builtin_amdgcn_mfma_f32_16x16x32_bf16(ah[kk], bh, acc, 0, 0, 0);
                if (xf32) {
                    short8 bl = *(const short8*)((const char*)Wtl + ba);
                    acc = __builtin_amdgcn_mfma_f32_16x16x32_bf16(ah[kk], bl, acc, 0, 0, 0);
                    acc = __builtin_amdgcn_mfma_f32_16x16x32_bf16(al[kk], bh, acc, 0, 0, 0);
                }
            }
            #pragma unroll
            for (int j = 0; j < 4; ++j) {
                int row = row0 + g * 4 + j;   // C/D: col=lane&15, row=(lane>>4)*4+reg [m89]
                if (row < nNodes)
                    y[(size_t)row * D + col] = f2bf(acc[j]);
            }
        }
    }
}

// ---------- standalone GEMM (fallback path only): out = in @ W (+ b) ----------
__global__ __launch_bounds__(256) void gemm_kernel(
    const void* __restrict__ inv, const void* __restrict__ Wv,
    const void* __restrict__ bv, void* __restrict__ outv,
    int nNodes, const int* __restrict__ flags,
    int in_f32p, int out_f32p, int add_bias)
{
    __shared__ float Ws[D * D];   // 64 KB
    __shared__ float bs[D];

    const int xf32 = flags[0];
    const int in_f32  = (in_f32p  < 0) ? xf32 : in_f32p;
    const int out_f32 = (out_f32p < 0) ? xf32 : out_f32p;

    if (xf32) {
        const float* W = (const float*)Wv;
        for (int i = threadIdx.x; i < D * D; i += 256) Ws[i] = W[i];
        if (threadIdx.x < D)
            bs[threadIdx.x] = add_bias ? ((const float*)bv)[threadIdx.x] : 0.f;
    } else {
        const unsigned short* W = (const unsigned short*)Wv;
        for (int i = threadIdx.x; i < D * D; i += 256) Ws[i] = bf2f(W[i]);
        if (threadIdx.x < D)
            bs[threadIdx.x] = add_bias ? bf2f(((const unsigned short*)bv)[threadIdx.x]) : 0.f;
    }
    __syncthreads();

    const int cg = threadIdx.x & 31;
    const int rg = threadIdx.x >> 5;
    const int c = cg * 4;
    const int row0 = blockIdx.x * 64 + rg * 8;

    size_t rIdx[8];
    #pragma unroll
    for (int r = 0; r < 8; ++r) {
        int row = row0 + r;
        rIdx[r] = (size_t)(row < nNodes ? row : nNodes - 1);
    }

    float4 acc[8];
    #pragma unroll
    for (int r = 0; r < 8; ++r)
        acc[r] = make_float4(bs[c], bs[c + 1], bs[c + 2], bs[c + 3]);

    if (in_f32) {
        const float* in = (const float*)inv;
        for (int k = 0; k < D; k += 4) {
            float4 w0 = *(const float4*)&Ws[(k + 0) * D + c];
            float4 w1 = *(const float4*)&Ws[(k + 1) * D + c];
            float4 w2 = *(const float4*)&Ws[(k + 2) * D + c];
            float4 w3 = *(const float4*)&Ws[(k + 3) * D + c];
            #pragma unroll
            for (int r = 0; r < 8; ++r) {
                float4 a = *(const float4*)(in + rIdx[r] * D + k);
                acc[r].x += a.x * w0.x + a.y * w1.x + a.z * w2.x + a.w * w3.x;
                acc[r].y += a.x * w0.y + a.y * w1.y + a.z * w2.y + a.w * w3.y;
                acc[r].z += a.x * w0.z + a.y * w1.z + a.z * w2.z + a.w * w3.z;
                acc[r].w += a.x * w0.w + a.y * w1.w + a.z * w2.w + a.w * w3.w;
            }
        }
    } else {
        const unsigned short* in = (const unsigned short*)inv;
        for (int k = 0; k < D; k += 4) {
            float4 w0 = *(const float4*)&Ws[(k + 0) * D + c];
            float4 w1 = *(const float4*)&Ws[(k + 1) * D + c];
            float4 w2 = *(const float4*)&Ws[(k + 2) * D + c];
            float4 w3 = *(const float4*)&Ws[(k + 3) * D + c];
            #pragma unroll
            for (int r = 0; r < 8; ++r) {
                ushort4 u = *(const ushort4*)(in + rIdx[r] * D + k);
                float ax = bf2f(u.x), ay = bf2f(u.y), az = bf2f(u.z), aw = bf2f(u.w);
                acc[r].x += ax * w0.x + ay * w1.x + az * w2.x + aw * w3.x;
                acc[r].y += ax * w0.y + ay * w1.y + az * w2.y + aw * w3.y;
                acc[r].z += ax * w0.z + ay * w1.z + az * w2.z + aw * w3.z;
                acc[r].w += ax * w0.w + ay * w1.w + az * w2.w + aw * w3.w;
            }
        }
    }

    #pragma unroll
    for (int r = 0; r < 8; ++r) {
        int row = row0 + r;
        if (row >= nNodes) break;
        if (out_f32) {
            ((float4*)outv)[(size_t)row * 32 + cg] = acc[r];
        } else {
            ushort4 o;
            o.x = f2bf(acc[r].x); o.y = f2bf(acc[r].y);
            o.z = f2bf(acc[r].z); o.w = f2bf(acc[r].w);
            ((ushort4*)outv)[(size_t)row * 32 + cg] = o;
        }
    }
}

// ---------- pass A: in-LDS counting sort per block, contiguous run write-out ----------
__global__ __launch_bounds__(256) void bin_edges(
    const void* __restrict__ eiv, int* __restrict__ gcnt, unsigned int* __restrict__ grp,
    int* __restrict__ ovfCnt, int* __restrict__ ovfHead, int2* __restrict__ ovf,
    int nEdges, int nNodes, int NB, int CAPB, int nPer)
{
    __shared__ int cnts[NBMAX];    // 16 KB: per-group count (this chunk)
    __shared__ int lrun[NBMAX];    // 16 KB: local scan / running ptr
    __shared__ int gbase[NBMAX];   // 16 KB: reserved global base
    __shared__ unsigned int stage[STAGE_E];   // 32 KB
    __shared__ int wsum[4];

    const int i64 = block_probe_i64(eiv, nNodes);
    const int tid = threadIdx.x;
    const int lane = tid & 63, wv = tid >> 6;
    const long long* ei64 = (const long long*)eiv;
    const int* ei32 = (const int*)eiv;

    const int e0 = blockIdx.x * nPer;
    int eEnd = e0 + nPer; if (eEnd > nEdges) eEnd = nEdges;

    for (int ch = e0; ch < eEnd; ch += STAGE_E) {
        int ce = ch + STAGE_E; if (ce > eEnd) ce = eEnd;

        for (int i = tid; i < NB; i += 256) cnts[i] = 0;
        __syncthreads();

        // P1: count this chunk's edges per group
        for (int e = ch + tid; e < ce; e += 256) {
            int d = i64 ? (int)ei64[(size_t)nEdges + e] : ei32[(size_t)nEdges + e];
            atomicAdd(&cnts[d >> 6], 1);
        }
        __syncthreads();

        // P2: reserve global runs + local exclusive scan (per-thread span + block scan)
        const int chunk = (NB + 255) / 256;
        const int g0 = tid * chunk;
        int g1 = g0 + chunk; if (g1 > NB) g1 = NB;
        int run = 0;
        for (int g = g0; g < g1; ++g) {
            lrun[g] = run;
            run += cnts[g];
            gbase[g] = (cnts[g] > 0) ? atomicAdd(&gcnt[(size_t)g * 16], cnts[g]) : 0;
        }
        int sc = run;
        #pragma unroll
        for (int o = 1; o < 64; o <<= 1) {
            int t = __shfl_up(sc, o);
            if (lane >= o) sc += t;
        }
        if (lane == 63) wsum[wv] = sc;
        __syncthreads();
        int wbase = 0;
        for (int i = 0; i < wv; ++i) wbase += wsum[i];
        const int tbase = wbase + sc - run;
        for (int g = g0; g < g1; ++g) lrun[g] += tbase;
        __syncthreads();

        // P3: scatter edges into LDS stage, sorted by group
        for (int e = ch + tid; e < ce; e += 256) {
            int s, d;
            if (i64) { s = (int)ei64[e]; d = (int)ei64[(size_t)nEdges + e]; }
            else     { s = ei32[e];      d = ei32[(size_t)nEdges + e]; }
            int g = d >> 6;
            unsigned int p = (unsigned int)s | ((unsigned int)(d & 63) << 20);
            int pos = atomicAdd(&lrun[g], 1);
            stage[pos] = p;
        }
        __syncthreads();

        // P4: contiguous per-run write-out (thread g-strided; run start = lrun-cnt)
        for (int g = tid; g < NB; g += 256) {
            int c = cnts[g];
            if (c == 0) continue;
            int st = lrun[g] - c;
            int gb = gbase[g];
            for (int i = 0; i < c; ++i) {
                unsigned int p = stage[st + i];
                int pos = gb + i;
                if (pos < CAPB) {
                    grp[(size_t)g * CAPB + pos] = p;
                } else {
                    int idx = atomicAdd(ovfCnt, 1);   // < nEdges guaranteed
                    int old = atomicExch(&ovfHead[g], idx);
                    ovf[idx] = make_int2(old, (int)p);
                }
            }
        }
        __syncthreads();   // protect cnts/lrun reuse next chunk
    }
}

// ---------- pass B: per-group counting-sort by row (LDS), then REGISTER accumulate ----------
__global__ __launch_bounds__(256, 4) void sort_accum(
    const void* __restrict__ xv,           // only for dtype probe
    const unsigned int* __restrict__ yu,   // y as bf16 pairs (N x 64 uints)
    const int* __restrict__ gcnt, const unsigned int* __restrict__ grp,
    const int* __restrict__ ovfHead, const int2* __restrict__ ovf,
    const void* __restrict__ bv, void* __restrict__ outv,
    int nNodes, int CAPB)
{
    __shared__ unsigned int sorted[CAPB_MAX];   // 8 KB
    __shared__ int rcnt[GRP], roff[GRP], rrun[GRP];

    const int xf32 = block_probe_xf32((const unsigned short*)xv);

    const int g = blockIdx.x;
    const int n0 = g << 6;
    const int tid = threadIdx.x;
    const int w = tid >> 6, lane = tid & 63;

    if (tid < GRP) rcnt[tid] = 0;
    __syncthreads();

    const int cnt = gcnt[(size_t)g * 16];
    const int m = cnt < CAPB ? cnt : CAPB;

    for (int i = tid; i < m; i += 256)
        atomicAdd(&rcnt[grp[(size_t)g * CAPB + i] >> 20], 1);
    __syncthreads();

    if (w == 0) {   // exclusive prefix over 64 bins
        int v = rcnt[lane];
        int sc = v;
        #pragma unroll
        for (int o = 1; o < 64; o <<= 1) {
            int t = __shfl_up(sc, o);
            if (lane >= o) sc += t;
        }
        roff[lane] = sc - v;
        rrun[lane] = sc - v;
    }
    __syncthreads();

    for (int i = tid; i < m; i += 256) {
        unsigned int p = grp[(size_t)g * CAPB + i];
        int pos = atomicAdd(&rrun[p >> 20], 1);
        sorted[pos] = p & 0xFFFFFu;
    }
    __syncthreads();

    const bool hasOvf = (cnt > CAPB);

    for (int r = w; r < GRP; r += 4) {
        int node = n0 + r;
        if (node >= nNodes) break;
        const int j0 = roff[r], dg = rcnt[r];

        float a0 = 0.f, a1 = 0.f, a2 = 0.f, a3 = 0.f;
        float b0 = 0.f, b1 = 0.f, b2 = 0.f, b3 = 0.f;
        int j = 0;
        for (; j + 4 <= dg; j += 4) {
            unsigned int s0 = sorted[j0 + j + 0];
            unsigned int s1 = sorted[j0 + j + 1];
            unsigned int s2 = sorted[j0 + j + 2];
            unsigned int s3 = sorted[j0 + j + 3];
            unsigned int u0 = yu[(size_t)s0 * 64 + lane];
            unsigned int u1 = yu[(size_t)s1 * 64 + lane];
            unsigned int u2 = yu[(size_t)s2 * 64 + lane];
            unsigned int u3 = yu[(size_t)s3 * 64 + lane];
            a0 += bits2f(u0 << 16); b0 += bits2f(u0 & 0xFFFF0000u);
            a1 += bits2f(u1 << 16); b1 += bits2f(u1 & 0xFFFF0000u);
            a2 += bits2f(u2 << 16); b2 += bits2f(u2 & 0xFFFF0000u);
            a3 += bits2f(u3 << 16); b3 += bits2f(u3 & 0xFFFF0000u);
        }
        for (; j < dg; ++j) {
            unsigned int s0 = sorted[j0 + j];
            unsigned int u0 = yu[(size_t)s0 * 64 + lane];
            a0 += bits2f(u0 << 16); b0 += bits2f(u0 & 0xFFFF0000u);
        }

        if (hasOvf) {
            int cur = ovfHead[g];
            while (cur >= 0) {
                int2 t = ovf[cur];
                unsigned int p = (unsigned int)t.y;
                if ((int)(p >> 20) == r) {
                    unsigned int u = yu[(size_t)(p & 0xFFFFFu) * 64 + lane];
                    a0 += bits2f(u << 16); b0 += bits2f(u & 0xFFFF0000u);
                }
                cur = t.x;
            }
        }

        float f0 = (a0 + a1) + (a2 + a3);
        float f1 = (b0 + b1) + (b2 + b3);

        if (xf32) {
            float2 bb = ((const float2*)bv)[lane];
            float2 o; o.x = f0 + bb.x; o.y = f1 + bb.y;
            ((float2*)outv)[(size_t)node * 64 + lane] = o;
        } else {
            unsigned int ub = ((const unsigned int*)bv)[lane];
            f0 += bits2f(ub << 16);
            f1 += bits2f(ub & 0xFFFF0000u);
            unsigned int o = ((unsigned int)f2bf(f0)) | (((unsigned int)f2bf(f1)) << 16);
            ((unsigned int*)outv)[(size_t)node * 64 + lane] = o;
        }
    }
}

// ---------- fallback scatter (atomics) if ws too small / N too large ----------
__global__ __launch_bounds__(256) void scatter_kernel(
    const void* __restrict__ xv, const void* __restrict__ eiv,
    float* __restrict__ agg, int nEdges, const int* __restrict__ flags)
{
    long long tid = (long long)blockIdx.x * 256 + threadIdx.x;
    int e = (int)(tid >> 5);
    if (e >= nEdges) return;
    int q = (int)tid & 31;

    const int xf32 = flags[0];
    int s, d;
    if (flags[1]) {
        const long long* ei = (const long long*)eiv;
        s = (int)ei[e]; d = (int)ei[(size_t)nEdges + e];
    } else {
        const int* ei = (const int*)eiv;
        s = ei[e]; d = ei[(size_t)nEdges + e];
    }
    float4 v;
    if (xf32) {
        v = ((const float4*)xv)[(size_t)s * 32 + q];
    } else {
        ushort4 u = ((const ushort4*)xv)[(size_t)s * 32 + q];
        v.x = bf2f(u.x); v.y = bf2f(u.y); v.z = bf2f(u.z); v.w = bf2f(u.w);
    }
    float* ap = agg + (size_t)d * D + q * 4;
    atomicAdd(ap + 0, v.x);
    atomicAdd(ap + 1, v.y);
    atomicAdd(ap + 2, v.z);
    atomicAdd(ap + 3, v.w);
}

static inline size_t alignup(size_t v, size_t a) { return (v + a - 1) & ~(a - 1); }

extern "C" void kernel_launch(void* const* d_in, const int* in_sizes, int n_in,
                              void* d_out, int out_size, void* d_ws, size_t ws_size,
                              hipStream_t stream) {
    const void* x  = d_in[0];
    const void* ei = d_in[1];
    const void* W  = d_in[2];
    const void* b  = d_in[3];

    const int nNodes = in_sizes[0] / D;
    const int nEdges = in_sizes[1] / 2;
    const int NB = (nNodes + GRP - 1) / GRP;

    // fast path ws layout:
    // flags(512) | gcnt[NB*16] | ovfCnt(256B) | ovfHead[NB] | ovf[E] int2 | grp[NB*CAPB] | y[N*D] bf16
    int CAPB = 0;
    size_t off_gcnt = 512, off_ovfc = 0, off_head = 0, off_ovf = 0, off_grp = 0, off_y = 0;
    if (nNodes < (1 << 20) && NB <= NBMAX) {
        int cap = CAPB_MAX;
        size_t ogcnt = 512;
        size_t oovfc = alignup(ogcnt + 64ull * NB, 256);
        size_t ohead = oovfc + 256;
        size_t oovf  = alignup(ohead + 4ull * NB, 256);
        size_t ogrp  = alignup(oovf + 8ull * nEdges, 256);
        size_t oy    = alignup(ogrp + 4ull * cap * NB, 512);
        size_t need  = oy + (size_t)nNodes * D * 2;   // y bf16
        if (ws_size >= need) {
            CAPB = cap; off_gcnt = ogcnt; off_ovfc = oovfc; off_head = ohead;
            off_ovf = oovf; off_grp = ogrp; off_y = oy;
        }
    }

    const int mblocks = (nNodes + 63) / 64;

    if (CAPB > 0) {
        int*          gcnt    = (int*)((char*)d_ws + off_gcnt);
        int*          ovfCnt  = (int*)((char*)d_ws + off_ovfc);
        int*          ovfHead = (int*)((char*)d_ws + off_head);
        int2*         ovf     = (int2*)((char*)d_ws + off_ovf);
        unsigned int* grp     = (unsigned int*)((char*)d_ws + off_grp);
        void*         y       = (void*)((char*)d_ws + off_y);

        const int zInts = (int)((off_head - off_gcnt) / 4);   // gcnt + ovfCnt region

        // 3-dispatch fast path: gemm(+zero-fold), bin, sort
        const int mtiles = (nNodes + 127) / 128;   // 128-row tiles, 512-thread blocks
        gemm_mfma<<<mtiles, 512, 0, stream>>>(x, W, y, nNodes, mtiles,
                                              gcnt, zInts, ovfHead, NB);

        const int ABLK = 256;   // ~4-edge runs/group/block: write-contiguity sweet spot
        const int nPer = (nEdges + ABLK - 1) / ABLK;
        bin_edges<<<ABLK, 256, 0, stream>>>(ei, gcnt, grp, ovfCnt, ovfHead, ovf,
                                            nEdges, nNodes, NB, CAPB, nPer);

        sort_accum<<<NB, 256, 0, stream>>>(x, (const unsigned int*)y, gcnt, grp,
                                           ovfHead, ovf, b, d_out,
                                           nNodes, CAPB);
    } else {
        // fallback: probe + atomic scatter into fp32 agg, then out = agg @ W + b
        int* flags = (int*)d_ws;
        probe_kernel<<<1, 64, 0, stream>>>((const unsigned short*)x, (const long long*)ei,
                                           nNodes, flags);
        float* agg = (float*)((char*)d_ws + 512);
        hipMemsetAsync(agg, 0, (size_t)nNodes * D * sizeof(float), stream);
        long long total = (long long)nEdges * 32;
        int sblocks = (int)((total + 255) / 256);
        scatter_kernel<<<sblocks, 256, 0, stream>>>(x, ei, agg, nEdges, flags);
        gemm_kernel<<<mblocks, 256, 0, stream>>>(agg, W, b, d_out, nNodes, flags,
                                                 /*in_f32*/1, /*out_f32*/-1, /*bias*/1);
    }
}

// Round 15
// 238.612 us; speedup vs baseline: 1.3329x; 1.3329x over previous
//
#include <hip/hip_runtime.h>
#include <hip/hip_bf16.h>

#define D 128
#define GRP 64            // nodes per group
#define NBMAX 4096        // max groups supported by fast path (N <= 256K)
#define CAPB_MAX 2048     // per-group capacity
#define STAGE_E 8192      // per-chunk LDS staging (edges)

typedef __attribute__((ext_vector_type(8))) short short8;
typedef __attribute__((ext_vector_type(4))) float f32x4;

__device__ __forceinline__ float bf2f(unsigned short u) {
    union { unsigned int i; float f; } c;
    c.i = ((unsigned int)u) << 16;
    return c.f;
}
__device__ __forceinline__ float bits2f(unsigned int i) {
    union { unsigned int i; float f; } c;
    c.i = i;
    return c.f;
}
__device__ __forceinline__ unsigned short f2bf(float f) {
    __hip_bfloat16 h = __float2bfloat16(f);
    return *(unsigned short*)&h;
}

// ---- per-block dtype probes (fast path; no separate probe dispatch) ----
__device__ __forceinline__ int block_probe_xf32(const unsigned short* x) {
    __shared__ int cntS;
    if (threadIdx.x == 0) cntS = 0;
    __syncthreads();
    int bad = 0;
    for (int i = threadIdx.x; i < 512; i += blockDim.x) {
        float v = bf2f(x[i]);
        if (!(fabsf(v) < 1e4f)) bad++;
    }
    if (bad) atomicAdd(&cntS, bad);
    __syncthreads();
    int r = (cntS > 2) ? 1 : 0;
    __syncthreads();
    return r;
}
__device__ __forceinline__ int block_probe_i64(const void* eiv, int nNodes) {
    __shared__ int okS;
    if (threadIdx.x == 0) okS = 1;
    __syncthreads();
    if (threadIdx.x < 64) {
        long long v = ((const long long*)eiv)[threadIdx.x];
        if (v < 0 || v >= (long long)nNodes) atomicAnd(&okS, 0);
    }
    __syncthreads();
    int r = okS;
    __syncthreads();
    return r;
}

// Probe kernel retained for the fallback path only.
__global__ __launch_bounds__(64) void probe_kernel(
    const unsigned short* __restrict__ x,
    const long long* __restrict__ ei64,
    int nNodes, int* __restrict__ flags)
{
    const int lane = threadIdx.x;
    int cnt = 0;
    for (int i = lane; i < 512; i += 64) {
        float v = bf2f(x[i]);
        if (!(fabsf(v) < 1e4f)) cnt++;
    }
    unsigned long long m1 = __ballot(cnt > 0);
    long long v = ei64[lane];
    int bad = (v < 0 || v >= (long long)nNodes) ? 1 : 0;
    unsigned long long m2 = __ballot(bad);
    if (lane == 0) {
        flags[0] = (__popcll(m1) > 2) ? 1 : 0;
        flags[1] = (m2 == 0) ? 1 : 0;
    }
}

// ---------- fast-path GEMM: y = x @ W via MFMA (fp32 -> hi/lo bf16 split) ----------
// 256 threads, 64-row tiles, grid-stride (r13 best config: 45us; 512-thread
// variant caused 7x partial-line write amplification -> 114us, reverted).
// Also zeroes gcnt/ovfCnt and sets ovfHead=-1 (stream order covers bin_edges).
__global__ __launch_bounds__(256, 2) void gemm_mfma(
    const void* __restrict__ xv, const void* __restrict__ Wv, void* __restrict__ yv,
    int nNodes, int nTiles,
    int* __restrict__ zbase, int zInts, int* __restrict__ mhead, int NB)
{
    __shared__ unsigned short Wth[D * D];   // 32 KB: hi(W)^T, swizzled
    __shared__ unsigned short Wtl[D * D];   // 32 KB: lo(W)^T (fp32 mode only)

    const int tid = threadIdx.x;

    // fold the old hipMemsetAsync calls into this kernel's prologue
    for (int i = blockIdx.x * 256 + tid; i < zInts; i += gridDim.x * 256) zbase[i] = 0;
    for (int i = blockIdx.x * 256 + tid; i < NB; i += gridDim.x * 256) mhead[i] = -1;

    const int xf32 = block_probe_xf32((const unsigned short*)xv);
    const int w = tid >> 6, l = tid & 63;
    const int lr = l & 15, g = l >> 4;

    if (xf32) {
        const float* W = (const float*)Wv;
        for (int i = tid; i < D * D; i += 256) {
            int c = i & 127, k = i >> 7;     // coalesced read (consecutive c)
            float wv = W[(size_t)k * D + c];
            unsigned short hi = f2bf(wv);
            unsigned short lo = f2bf(wv - bf2f(hi));
            int ba = (((c << 7) + k) << 1) ^ ((c & 7) << 4);
            *(unsigned short*)((char*)Wth + ba) = hi;
            *(unsigned short*)((char*)Wtl + ba) = lo;
        }
    } else {
        const unsigned short* W = (const unsigned short*)Wv;
        for (int i = tid; i < D * D / 2; i += 256) {
            int c = i & 127, k2 = i >> 7;
            unsigned int v0 = W[(size_t)(2 * k2) * D + c];
            unsigned int v1 = W[(size_t)(2 * k2 + 1) * D + c];
            unsigned int pk = v0 | (v1 << 16);
            int ba = (((c << 7) + 2 * k2) << 1) ^ ((c & 7) << 4);
            *(unsigned int*)((char*)Wth + ba) = pk;
        }
    }
    __syncthreads();

    unsigned short* y = (unsigned short*)yv;

    for (int t = blockIdx.x; t < nTiles; t += gridDim.x) {
        const int row0 = t * 64 + w * 16;
        int arow = row0 + lr; if (arow >= nNodes) arow = nNodes - 1;

        short8 ah[4], al[4];
        if (xf32) {
            const float* xr = (const float*)xv + (size_t)arow * D;
            #pragma unroll
            for (int kk = 0; kk < 4; ++kk) {
                float f[8];
                *(float4*)&f[0] = *(const float4*)(xr + kk * 32 + g * 8);
                *(float4*)&f[4] = *(const float4*)(xr + kk * 32 + g * 8 + 4);
                #pragma unroll
                for (int i = 0; i < 8; ++i) {
                    unsigned short hi = f2bf(f[i]);
                    ah[kk][i] = (short)hi;
                    al[kk][i] = (short)f2bf(f[i] - bf2f(hi));
                }
            }
        } else {
            const char* xrow = (const char*)xv + (size_t)arow * (D * 2);
            #pragma unroll
            for (int kk = 0; kk < 4; ++kk)
                ah[kk] = *(const short8*)(xrow + (kk << 6) + (g << 4));
        }

        #pragma unroll
        for (int c = 0; c < 8; ++c) {
            const int col = c * 16 + lr;
            f32x4 acc = {0.f, 0.f, 0.f, 0.f};
            #pragma unroll
            for (int kk = 0; kk < 4; ++kk) {
                int ba = ((col << 8) + (kk << 6) + (g << 4)) ^ ((col & 7) << 4);
                short8 bh = *(const short8*)((const char*)Wth + ba);
                acc = __builtin_amdgcn_mfma_f32_16x16x32_bf16(ah[kk], bh, acc, 0, 0, 0);
                if (xf32) {
                    short8 bl = *(const short8*)((const char*)Wtl + ba);
                    acc = __builtin_amdgcn_mfma_f32_16x16x32_bf16(ah[kk], bl, acc, 0, 0, 0);
                    acc = __builtin_amdgcn_mfma_f32_16x16x32_bf16(al[kk], bh, acc, 0, 0, 0);
                }
            }
            #pragma unroll
            for (int j = 0; j < 4; ++j) {
                int row = row0 + g * 4 + j;   // C/D: col=lane&15, row=(lane>>4)*4+reg [m89]
                if (row < nNodes)
                    y[(size_t)row * D + col] = f2bf(acc[j]);
            }
        }
    }
}

// ---------- standalone GEMM (fallback path only): out = in @ W (+ b) ----------
__global__ __launch_bounds__(256) void gemm_kernel(
    const void* __restrict__ inv, const void* __restrict__ Wv,
    const void* __restrict__ bv, void* __restrict__ outv,
    int nNodes, const int* __restrict__ flags,
    int in_f32p, int out_f32p, int add_bias)
{
    __shared__ float Ws[D * D];   // 64 KB
    __shared__ float bs[D];

    const int xf32 = flags[0];
    const int in_f32  = (in_f32p  < 0) ? xf32 : in_f32p;
    const int out_f32 = (out_f32p < 0) ? xf32 : out_f32p;

    if (xf32) {
        const float* W = (const float*)Wv;
        for (int i = threadIdx.x; i < D * D; i += 256) Ws[i] = W[i];
        if (threadIdx.x < D)
            bs[threadIdx.x] = add_bias ? ((const float*)bv)[threadIdx.x] : 0.f;
    } else {
        const unsigned short* W = (const unsigned short*)Wv;
        for (int i = threadIdx.x; i < D * D; i += 256) Ws[i] = bf2f(W[i]);
        if (threadIdx.x < D)
            bs[threadIdx.x] = add_bias ? bf2f(((const unsigned short*)bv)[threadIdx.x]) : 0.f;
    }
    __syncthreads();

    const int cg = threadIdx.x & 31;
    const int rg = threadIdx.x >> 5;
    const int c = cg * 4;
    const int row0 = blockIdx.x * 64 + rg * 8;

    size_t rIdx[8];
    #pragma unroll
    for (int r = 0; r < 8; ++r) {
        int row = row0 + r;
        rIdx[r] = (size_t)(row < nNodes ? row : nNodes - 1);
    }

    float4 acc[8];
    #pragma unroll
    for (int r = 0; r < 8; ++r)
        acc[r] = make_float4(bs[c], bs[c + 1], bs[c + 2], bs[c + 3]);

    if (in_f32) {
        const float* in = (const float*)inv;
        for (int k = 0; k < D; k += 4) {
            float4 w0 = *(const float4*)&Ws[(k + 0) * D + c];
            float4 w1 = *(const float4*)&Ws[(k + 1) * D + c];
            float4 w2 = *(const float4*)&Ws[(k + 2) * D + c];
            float4 w3 = *(const float4*)&Ws[(k + 3) * D + c];
            #pragma unroll
            for (int r = 0; r < 8; ++r) {
                float4 a = *(const float4*)(in + rIdx[r] * D + k);
                acc[r].x += a.x * w0.x + a.y * w1.x + a.z * w2.x + a.w * w3.x;
                acc[r].y += a.x * w0.y + a.y * w1.y + a.z * w2.y + a.w * w3.y;
                acc[r].z += a.x * w0.z + a.y * w1.z + a.z * w2.z + a.w * w3.z;
                acc[r].w += a.x * w0.w + a.y * w1.w + a.z * w2.w + a.w * w3.w;
            }
        }
    } else {
        const unsigned short* in = (const unsigned short*)inv;
        for (int k = 0; k < D; k += 4) {
            float4 w0 = *(const float4*)&Ws[(k + 0) * D + c];
            float4 w1 = *(const float4*)&Ws[(k + 1) * D + c];
            float4 w2 = *(const float4*)&Ws[(k + 2) * D + c];
            float4 w3 = *(const float4*)&Ws[(k + 3) * D + c];
            #pragma unroll
            for (int r = 0; r < 8; ++r) {
                ushort4 u = *(const ushort4*)(in + rIdx[r] * D + k);
                float ax = bf2f(u.x), ay = bf2f(u.y), az = bf2f(u.z), aw = bf2f(u.w);
                acc[r].x += ax * w0.x + ay * w1.x + az * w2.x + aw * w3.x;
                acc[r].y += ax * w0.y + ay * w1.y + az * w2.y + aw * w3.y;
                acc[r].z += ax * w0.z + ay * w1.z + az * w2.z + aw * w3.z;
                acc[r].w += ax * w0.w + ay * w1.w + az * w2.w + aw * w3.w;
            }
        }
    }

    #pragma unroll
    for (int r = 0; r < 8; ++r) {
        int row = row0 + r;
        if (row >= nNodes) break;
        if (out_f32) {
            ((float4*)outv)[(size_t)row * 32 + cg] = acc[r];
        } else {
            ushort4 o;
            o.x = f2bf(acc[r].x); o.y = f2bf(acc[r].y);
            o.z = f2bf(acc[r].z); o.w = f2bf(acc[r].w);
            ((ushort4*)outv)[(size_t)row * 32 + cg] = o;
        }
    }
}

// ---------- pass A: in-LDS counting sort per block, contiguous run write-out ----------
__global__ __launch_bounds__(256) void bin_edges(
    const void* __restrict__ eiv, int* __restrict__ gcnt, unsigned int* __restrict__ grp,
    int* __restrict__ ovfCnt, int* __restrict__ ovfHead, int2* __restrict__ ovf,
    int nEdges, int nNodes, int NB, int CAPB, int nPer)
{
    __shared__ int cnts[NBMAX];    // 16 KB: per-group count (this chunk)
    __shared__ int lrun[NBMAX];    // 16 KB: local scan / running ptr
    __shared__ int gbase[NBMAX];   // 16 KB: reserved global base
    __shared__ unsigned int stage[STAGE_E];   // 32 KB
    __shared__ int wsum[4];

    const int i64 = block_probe_i64(eiv, nNodes);
    const int tid = threadIdx.x;
    const int lane = tid & 63, wv = tid >> 6;
    const long long* ei64 = (const long long*)eiv;
    const int* ei32 = (const int*)eiv;

    const int e0 = blockIdx.x * nPer;
    int eEnd = e0 + nPer; if (eEnd > nEdges) eEnd = nEdges;

    for (int ch = e0; ch < eEnd; ch += STAGE_E) {
        int ce = ch + STAGE_E; if (ce > eEnd) ce = eEnd;

        for (int i = tid; i < NB; i += 256) cnts[i] = 0;
        __syncthreads();

        // P1: count this chunk's edges per group
        for (int e = ch + tid; e < ce; e += 256) {
            int d = i64 ? (int)ei64[(size_t)nEdges + e] : ei32[(size_t)nEdges + e];
            atomicAdd(&cnts[d >> 6], 1);
        }
        __syncthreads();

        // P2: reserve global runs + local exclusive scan (per-thread span + block scan)
        const int chunk = (NB + 255) / 256;
        const int g0 = tid * chunk;
        int g1 = g0 + chunk; if (g1 > NB) g1 = NB;
        int run = 0;
        for (int g = g0; g < g1; ++g) {
            lrun[g] = run;
            run += cnts[g];
            gbase[g] = (cnts[g] > 0) ? atomicAdd(&gcnt[(size_t)g * 16], cnts[g]) : 0;
        }
        int sc = run;
        #pragma unroll
        for (int o = 1; o < 64; o <<= 1) {
            int t = __shfl_up(sc, o);
            if (lane >= o) sc += t;
        }
        if (lane == 63) wsum[wv] = sc;
        __syncthreads();
        int wbase = 0;
        for (int i = 0; i < wv; ++i) wbase += wsum[i];
        const int tbase = wbase + sc - run;
        for (int g = g0; g < g1; ++g) lrun[g] += tbase;
        __syncthreads();

        // P3: scatter edges into LDS stage, sorted by group
        for (int e = ch + tid; e < ce; e += 256) {
            int s, d;
            if (i64) { s = (int)ei64[e]; d = (int)ei64[(size_t)nEdges + e]; }
            else     { s = ei32[e];      d = ei32[(size_t)nEdges + e]; }
            int g = d >> 6;
            unsigned int p = (unsigned int)s | ((unsigned int)(d & 63) << 20);
            int pos = atomicAdd(&lrun[g], 1);
            stage[pos] = p;
        }
        __syncthreads();

        // P4: contiguous per-run write-out (thread g-strided; run start = lrun-cnt)
        for (int g = tid; g < NB; g += 256) {
            int c = cnts[g];
            if (c == 0) continue;
            int st = lrun[g] - c;
            int gb = gbase[g];
            for (int i = 0; i < c; ++i) {
                unsigned int p = stage[st + i];
                int pos = gb + i;
                if (pos < CAPB) {
                    grp[(size_t)g * CAPB + pos] = p;
                } else {
                    int idx = atomicAdd(ovfCnt, 1);   // < nEdges guaranteed
                    int old = atomicExch(&ovfHead[g], idx);
                    ovf[idx] = make_int2(old, (int)p);
                }
            }
        }
        __syncthreads();   // protect cnts/lrun reuse next chunk
    }
}

// ---------- pass B: per-group counting-sort by row (LDS), then REGISTER accumulate ----------
__global__ __launch_bounds__(256, 4) void sort_accum(
    const void* __restrict__ xv,           // only for dtype probe
    const unsigned int* __restrict__ yu,   // y as bf16 pairs (N x 64 uints)
    const int* __restrict__ gcnt, const unsigned int* __restrict__ grp,
    const int* __restrict__ ovfHead, const int2* __restrict__ ovf,
    const void* __restrict__ bv, void* __restrict__ outv,
    int nNodes, int CAPB)
{
    __shared__ unsigned int sorted[CAPB_MAX];   // 8 KB
    __shared__ int rcnt[GRP], roff[GRP], rrun[GRP];

    const int xf32 = block_probe_xf32((const unsigned short*)xv);

    const int g = blockIdx.x;
    const int n0 = g << 6;
    const int tid = threadIdx.x;
    const int w = tid >> 6, lane = tid & 63;

    if (tid < GRP) rcnt[tid] = 0;
    __syncthreads();

    const int cnt = gcnt[(size_t)g * 16];
    const int m = cnt < CAPB ? cnt : CAPB;

    for (int i = tid; i < m; i += 256)
        atomicAdd(&rcnt[grp[(size_t)g * CAPB + i] >> 20], 1);
    __syncthreads();

    if (w == 0) {   // exclusive prefix over 64 bins
        int v = rcnt[lane];
        int sc = v;
        #pragma unroll
        for (int o = 1; o < 64; o <<= 1) {
            int t = __shfl_up(sc, o);
            if (lane >= o) sc += t;
        }
        roff[lane] = sc - v;
        rrun[lane] = sc - v;
    }
    __syncthreads();

    for (int i = tid; i < m; i += 256) {
        unsigned int p = grp[(size_t)g * CAPB + i];
        int pos = atomicAdd(&rrun[p >> 20], 1);
        sorted[pos] = p & 0xFFFFFu;
    }
    __syncthreads();

    const bool hasOvf = (cnt > CAPB);

    for (int r = w; r < GRP; r += 4) {
        int node = n0 + r;
        if (node >= nNodes) break;
        const int j0 = roff[r], dg = rcnt[r];

        float a0 = 0.f, a1 = 0.f, a2 = 0.f, a3 = 0.f;
        float b0 = 0.f, b1 = 0.f, b2 = 0.f, b3 = 0.f;
        int j = 0;
        for (; j + 4 <= dg; j += 4) {
            unsigned int s0 = sorted[j0 + j + 0];
            unsigned int s1 = sorted[j0 + j + 1];
            unsigned int s2 = sorted[j0 + j + 2];
            unsigned int s3 = sorted[j0 + j + 3];
            unsigned int u0 = yu[(size_t)s0 * 64 + lane];
            unsigned int u1 = yu[(size_t)s1 * 64 + lane];
            unsigned int u2 = yu[(size_t)s2 * 64 + lane];
            unsigned int u3 = yu[(size_t)s3 * 64 + lane];
            a0 += bits2f(u0 << 16); b0 += bits2f(u0 & 0xFFFF0000u);
            a1 += bits2f(u1 << 16); b1 += bits2f(u1 & 0xFFFF0000u);
            a2 += bits2f(u2 << 16); b2 += bits2f(u2 & 0xFFFF0000u);
            a3 += bits2f(u3 << 16); b3 += bits2f(u3 & 0xFFFF0000u);
        }
        for (; j < dg; ++j) {
            unsigned int s0 = sorted[j0 + j];
            unsigned int u0 = yu[(size_t)s0 * 64 + lane];
            a0 += bits2f(u0 << 16); b0 += bits2f(u0 & 0xFFFF0000u);
        }

        if (hasOvf) {
            int cur = ovfHead[g];
            while (cur >= 0) {
                int2 t = ovf[cur];
                unsigned int p = (unsigned int)t.y;
                if ((int)(p >> 20) == r) {
                    unsigned int u = yu[(size_t)(p & 0xFFFFFu) * 64 + lane];
                    a0 += bits2f(u << 16); b0 += bits2f(u & 0xFFFF0000u);
                }
                cur = t.x;
            }
        }

        float f0 = (a0 + a1) + (a2 + a3);
        float f1 = (b0 + b1) + (b2 + b3);

        if (xf32) {
            float2 bb = ((const float2*)bv)[lane];
            float2 o; o.x = f0 + bb.x; o.y = f1 + bb.y;
            ((float2*)outv)[(size_t)node * 64 + lane] = o;
        } else {
            unsigned int ub = ((const unsigned int*)bv)[lane];
            f0 += bits2f(ub << 16);
            f1 += bits2f(ub & 0xFFFF0000u);
            unsigned int o = ((unsigned int)f2bf(f0)) | (((unsigned int)f2bf(f1)) << 16);
            ((unsigned int*)outv)[(size_t)node * 64 + lane] = o;
        }
    }
}

// ---------- fallback scatter (atomics) if ws too small / N too large ----------
__global__ __launch_bounds__(256) void scatter_kernel(
    const void* __restrict__ xv, const void* __restrict__ eiv,
    float* __restrict__ agg, int nEdges, const int* __restrict__ flags)
{
    long long tid = (long long)blockIdx.x * 256 + threadIdx.x;
    int e = (int)(tid >> 5);
    if (e >= nEdges) return;
    int q = (int)tid & 31;

    const int xf32 = flags[0];
    int s, d;
    if (flags[1]) {
        const long long* ei = (const long long*)eiv;
        s = (int)ei[e]; d = (int)ei[(size_t)nEdges + e];
    } else {
        const int* ei = (const int*)eiv;
        s = ei[e]; d = ei[(size_t)nEdges + e];
    }
    float4 v;
    if (xf32) {
        v = ((const float4*)xv)[(size_t)s * 32 + q];
    } else {
        ushort4 u = ((const ushort4*)xv)[(size_t)s * 32 + q];
        v.x = bf2f(u.x); v.y = bf2f(u.y); v.z = bf2f(u.z); v.w = bf2f(u.w);
    }
    float* ap = agg + (size_t)d * D + q * 4;
    atomicAdd(ap + 0, v.x);
    atomicAdd(ap + 1, v.y);
    atomicAdd(ap + 2, v.z);
    atomicAdd(ap + 3, v.w);
}

static inline size_t alignup(size_t v, size_t a) { return (v + a - 1) & ~(a - 1); }

extern "C" void kernel_launch(void* const* d_in, const int* in_sizes, int n_in,
                              void* d_out, int out_size, void* d_ws, size_t ws_size,
                              hipStream_t stream) {
    const void* x  = d_in[0];
    const void* ei = d_in[1];
    const void* W  = d_in[2];
    const void* b  = d_in[3];

    const int nNodes = in_sizes[0] / D;
    const int nEdges = in_sizes[1] / 2;
    const int NB = (nNodes + GRP - 1) / GRP;

    // fast path ws layout:
    // flags(512) | gcnt[NB*16] | ovfCnt(256B) | ovfHead[NB] | ovf[E] int2 | grp[NB*CAPB] | y[N*D] bf16
    int CAPB = 0;
    size_t off_gcnt = 512, off_ovfc = 0, off_head = 0, off_ovf = 0, off_grp = 0, off_y = 0;
    if (nNodes < (1 << 20) && NB <= NBMAX) {
        int cap = CAPB_MAX;
        size_t ogcnt = 512;
        size_t oovfc = alignup(ogcnt + 64ull * NB, 256);
        size_t ohead = oovfc + 256;
        size_t oovf  = alignup(ohead + 4ull * NB, 256);
        size_t ogrp  = alignup(oovf + 8ull * nEdges, 256);
        size_t oy    = alignup(ogrp + 4ull * cap * NB, 512);
        size_t need  = oy + (size_t)nNodes * D * 2;   // y bf16
        if (ws_size >= need) {
            CAPB = cap; off_gcnt = ogcnt; off_ovfc = oovfc; off_head = ohead;
            off_ovf = oovf; off_grp = ogrp; off_y = oy;
        }
    }

    const int mblocks = (nNodes + 63) / 64;

    if (CAPB > 0) {
        int*          gcnt    = (int*)((char*)d_ws + off_gcnt);
        int*          ovfCnt  = (int*)((char*)d_ws + off_ovfc);
        int*          ovfHead = (int*)((char*)d_ws + off_head);
        int2*         ovf     = (int2*)((char*)d_ws + off_ovf);
        unsigned int* grp     = (unsigned int*)((char*)d_ws + off_grp);
        void*         y       = (void*)((char*)d_ws + off_y);

        const int zInts = (int)((off_head - off_gcnt) / 4);   // gcnt + ovfCnt region

        // 3-dispatch fast path: gemm(+zero-fold), bin, sort
        int gblocks = mblocks < 512 ? mblocks : 512;   // 2 blocks/CU, grid-stride tiles
        gemm_mfma<<<gblocks, 256, 0, stream>>>(x, W, y, nNodes, mblocks,
                                               gcnt, zInts, ovfHead, NB);

        const int ABLK = 256;   // ~4-edge runs/group/block: write-contiguity sweet spot
        const int nPer = (nEdges + ABLK - 1) / ABLK;
        bin_edges<<<ABLK, 256, 0, stream>>>(ei, gcnt, grp, ovfCnt, ovfHead, ovf,
                                            nEdges, nNodes, NB, CAPB, nPer);

        sort_accum<<<NB, 256, 0, stream>>>(x, (const unsigned int*)y, gcnt, grp,
                                           ovfHead, ovf, b, d_out,
                                           nNodes, CAPB);
    } else {
        // fallback: probe + atomic scatter into fp32 agg, then out = agg @ W + b
        int* flags = (int*)d_ws;
        probe_kernel<<<1, 64, 0, stream>>>((const unsigned short*)x, (const long long*)ei,
                                           nNodes, flags);
        float* agg = (float*)((char*)d_ws + 512);
        hipMemsetAsync(agg, 0, (size_t)nNodes * D * sizeof(float), stream);
        long long total = (long long)nEdges * 32;
        int sblocks = (int)((total + 255) / 256);
        scatter_kernel<<<sblocks, 256, 0, stream>>>(x, ei, agg, nEdges, flags);
        gemm_kernel<<<mblocks, 256, 0, stream>>>(agg, W, b, d_out, nNodes, flags,
                                                 /*in_f32*/1, /*out_f32*/-1, /*bias*/1);
    }
}